// Round 11
// baseline (195.269 us; speedup 1.0000x reference)
//
#include <hip/hip_runtime.h>
#include <math.h>

// ---------------- workspace layout (float offsets; OUT* used as bf16/ushort) ----
#define WS_STATS 0         // 24 floats: [layer][S_r..S_k, Q_r..Q_k]
#define WS_W1    32        // 16*4*9   = 576      layout [s(4)][k(9)][oc(16)]
#define WS_W2    640       // 64*16*9  = 9216     layout [ic(16)][k(9)][oc(64)]
#define WS_W3    9856      // 128*64*9 = 73728    layout [ic(64)][k(9)][oc(128)]
#define WS_WFC   83584     // 2048*16  = 32768    layout [row(2048)][col(16)]
#define WS_POOL  116352    // 256*200  = 51200
#define WS_OUT1  167552    // bf16: 256*16*32*32 ushorts
#define WS_OUT2  4361856   // bf16: 256*64*16*16 ushorts
#define WS_OUT3  8556160   // bf16: 256*128*8*8  ushorts

// Hamilton block table: T[a][b] -> (component, sign)
__device__ const int   d_TC[4][4] = {{0,1,2,3},{1,0,3,2},{2,3,0,1},{3,2,1,0}};
__device__ const float d_TS[4][4] = {{1.f,-1.f,-1.f,-1.f},{1.f,1.f,-1.f,1.f},
                                     {1.f,1.f,1.f,-1.f},{1.f,-1.f,1.f,1.f}};

__device__ __forceinline__ unsigned short f2bf(float f) {  // RNE fp32->bf16
    unsigned u = __float_as_uint(f);
    u += 0x7FFFu + ((u >> 16) & 1u);
    return (unsigned short)(u >> 16);
}
__device__ __forceinline__ float bf_lo(unsigned p) { return __uint_as_float(p << 16); }
__device__ __forceinline__ float bf_hi(unsigned p) { return __uint_as_float(p & 0xFFFF0000u); }

// ---------------- persistent prep+mean: grid 1024, 50 channels/block ----------------
__global__ __launch_bounds__(256) void prepmean_kernel(
    const float* __restrict__ x, float* __restrict__ pooled,
    const float* l1r, const float* l1i, const float* l1j, const float* l1k,
    const float* l2r, const float* l2i, const float* l2j, const float* l2k,
    const float* l3r, const float* l3i, const float* l3j, const float* l3k,
    const float* fcr, const float* fci, const float* fcj, const float* fck,
    float* ws)
{
    const int blk = blockIdx.x, t = threadIdx.x;
    const int lane = t & 63, wv = t >> 6;
    int tid = blk * 256 + t;
    const int nthr = 1024 * 256;
    if (tid < 24) ws[WS_STATS + tid] = 0.f;

    { // W1: [s(4)][k(9)][oc(16)]
        const float* cp[4] = {l1r, l1i, l1j, l1k};
        for (int e = tid; e < 576; e += nthr) {
            int s = e / 144, rem = e % 144, k = rem / 16, oc = rem % 16;
            int p = oc >> 2, o = oc & 3;
            ws[WS_W1 + e] = d_TS[p][s] * cp[d_TC[p][s]][o * 9 + k];
        }
    }
    { // W2: [ic(16)][k(9)][oc(64)]
        const float* cp[4] = {l2r, l2i, l2j, l2k};
        for (int e = tid; e < 9216; e += nthr) {
            int oc = e & 63, k = (e >> 6) % 9, ic = e / 576;
            int p = oc >> 4, o = oc & 15, s = ic >> 2, ii = ic & 3;
            ws[WS_W2 + e] = d_TS[p][s] * cp[d_TC[p][s]][(o * 4 + ii) * 9 + k];
        }
    }
    { // W3: [ic(64)][k(9)][oc(128)]
        const float* cp[4] = {l3r, l3i, l3j, l3k};
        for (int e = tid; e < 73728; e += nthr) {
            int oc = e & 127, k = (e >> 7) % 9, ic = e / 1152;
            int p = oc >> 5, o = oc & 31, s = ic >> 4, ii = ic & 15;
            ws[WS_W3 + e] = d_TS[p][s] * cp[d_TC[p][s]][(o * 16 + ii) * 9 + k];
        }
    }
    { // WFC: 2048 x 16
        const float* cp[4] = {fcr, fci, fcj, fck};
        for (int e = tid; e < 32768; e += nthr) {
            int R = e >> 4, C = e & 15;
            int p = R >> 9, rr = R & 511, q = C >> 2, cc = C & 3;
            ws[WS_WFC + e] = d_TS[q][p] * cp[d_TC[q][p]][rr * 4 + cc];
        }
    }
    // channel means: 50 channels per block, one channel per wave-iteration
    int base = blk * 50;
    for (int i = wv; i < 50; i += 4) {
        const float4* src = reinterpret_cast<const float4*>(x + (size_t)(base + i) * 1024);
        float s = 0.f;
        #pragma unroll
        for (int j = 0; j < 4; j++) {
            float4 v = src[lane + 64 * j];
            s += v.x + v.y + v.z + v.w;
        }
        #pragma unroll
        for (int off = 32; off; off >>= 1) s += __shfl_xor(s, off, 64);
        if (lane == 0) pooled[base + i] = s * (1.0f / 1024.0f);
    }
}

// ---------------- conv1 (+in-block top-3): 4->16 ch, 32x32; grid 2048; bf16 out ----
__global__ __launch_bounds__(256) void conv1_kernel(const float* __restrict__ x,
                                                    const float* __restrict__ pooled,
                                                    const float* __restrict__ w_eca,
                                                    const float* __restrict__ W1,
                                                    const float* __restrict__ b1,
                                                    unsigned short* __restrict__ out1,
                                                    float* __restrict__ stats)
{
    __shared__ float smem[3][6][36];
    __shared__ float rs[8];
    __shared__ int idx_s[3];
    int b = blockIdx.x >> 3, rg = blockIdx.x & 7;
    int t = threadIdx.x;
    if (t < 8) rs[t] = 0.f;
    if (t < 64) {
        float w = w_eca[0];
        float v[4]; int c[4];
        #pragma unroll
        for (int i = 0; i < 4; i++) {
            int ch = t + 64 * i;
            c[i] = ch;
            v[i] = (ch < 200) ? w * pooled[b * 200 + ch] : -INFINITY;
        }
        for (int k = 0; k < 3; k++) {
            float bv = -INFINITY; int bi = 0x3fffffff;
            #pragma unroll
            for (int i = 0; i < 4; i++)
                if (v[i] > bv || (v[i] == bv && c[i] < bi)) { bv = v[i]; bi = c[i]; }
            for (int off = 32; off; off >>= 1) {
                float ov = __shfl_xor(bv, off, 64);
                int   oi = __shfl_xor(bi, off, 64);
                if (ov > bv || (ov == bv && oi < bi)) { bv = ov; bi = oi; }
            }
            if (t == 0) idx_s[k] = bi;
            #pragma unroll
            for (int i = 0; i < 4; i++) if (c[i] == bi) v[i] = -INFINITY;
        }
    }
    __syncthreads();
    for (int i = t; i < 648; i += 256) {
        int s = i / 216, rem = i % 216, r = rem / 36, cc = rem % 36;
        int gr = rg * 4 - 1 + r, gc = cc - 1;
        float v = 0.f;
        if (gr >= 0 && gr < 32 && gc >= 0 && gc < 32)
            v = x[((size_t)b * 200 + idx_s[s]) * 1024 + gr * 32 + gc];
        smem[s][r][cc] = v;
    }
    __syncthreads();

    int oc = t & 15, rp = (t >> 4) & 3, ch = t >> 6;
    float bb = b1[oc];
    float acc[8];
    #pragma unroll
    for (int px = 0; px < 8; px++) acc[px] = bb;

    #pragma unroll
    for (int s = 0; s < 3; s++) {
        float w[9];
        #pragma unroll
        for (int k = 0; k < 9; k++) w[k] = W1[((s + 1) * 9 + k) * 16 + oc];
        float rowv[3][12];
        #pragma unroll
        for (int dy = 0; dy < 3; dy++) {
            const float* rb = &smem[s][rp + dy][ch * 8];
            float4 a = *reinterpret_cast<const float4*>(rb);
            float4 bq = *reinterpret_cast<const float4*>(rb + 4);
            float4 cq = *reinterpret_cast<const float4*>(rb + 8);
            rowv[dy][0]=a.x;  rowv[dy][1]=a.y;  rowv[dy][2]=a.z;  rowv[dy][3]=a.w;
            rowv[dy][4]=bq.x; rowv[dy][5]=bq.y; rowv[dy][6]=bq.z; rowv[dy][7]=bq.w;
            rowv[dy][8]=cq.x; rowv[dy][9]=cq.y; rowv[dy][10]=cq.z; rowv[dy][11]=cq.w;
        }
        #pragma unroll
        for (int dy = 0; dy < 3; dy++)
            #pragma unroll
            for (int px = 0; px < 8; px++) {
                float a = acc[px];
                a = fmaf(w[dy*3+0], rowv[dy][px],   a);
                a = fmaf(w[dy*3+1], rowv[dy][px+1], a);
                a = fmaf(w[dy*3+2], rowv[dy][px+2], a);
                acc[px] = a;
            }
    }
    int row = rg * 4 + rp;
    unsigned short* outb = out1 + ((size_t)b * 16 + oc) * 1024 + row * 32 + ch * 8;
    uint4 pk;
    pk.x = (unsigned)f2bf(acc[0]) | ((unsigned)f2bf(acc[1]) << 16);
    pk.y = (unsigned)f2bf(acc[2]) | ((unsigned)f2bf(acc[3]) << 16);
    pk.z = (unsigned)f2bf(acc[4]) | ((unsigned)f2bf(acc[5]) << 16);
    pk.w = (unsigned)f2bf(acc[6]) | ((unsigned)f2bf(acc[7]) << 16);
    *reinterpret_cast<uint4*>(outb) = pk;
    float sv = 0.f, qv = 0.f;
    #pragma unroll
    for (int px = 0; px < 8; px++) { sv += acc[px]; qv += acc[px] * acc[px]; }
    int g = oc >> 2;
    atomicAdd(&rs[g], sv); atomicAdd(&rs[4 + g], qv);
    __syncthreads();
    if (t < 8) atomicAdd(&stats[t], rs[t]);
}

// ---------------- conv2 (+fused bn1/relu/pool): 16->64 ch; grid 2048 x 128thr ----
__global__ __launch_bounds__(128) void conv2_kernel(const unsigned short* __restrict__ out1,
                                                    const float* __restrict__ W2,
                                                    const float* __restrict__ b2,
                                                    const float* __restrict__ bn1g,
                                                    const float* __restrict__ bn1b,
                                                    unsigned short* __restrict__ out2,
                                                    float* __restrict__ stats)
{
    __shared__ float smem[16][4][20];
    __shared__ float rs[8];
    __shared__ float sc[16], sh[16];
    int b = blockIdx.x >> 3, rq = blockIdx.x & 7;
    int t = threadIdx.x;
    if (t < 8) rs[t] = 0.f;
    if (t < 16) {
        const float invN = 1.0f / 1048576.0f;
        float var = 0.f;
        #pragma unroll
        for (int g = 0; g < 4; g++) {
            float S = stats[g], Q = stats[4 + g];
            var += Q - S * S * invN;
        }
        var *= invN;
        float inv = 1.0f / sqrtf(var + 1e-5f);
        float scale = bn1g[t & 3] * inv;
        sc[t] = scale;
        sh[t] = bn1b[t] - stats[t >> 2] * invN * scale;
    }
    __syncthreads();
    for (int i = t; i < 1280; i += 128) {
        int ic = i / 80, rem = i % 80, r = rem / 20, cc = rem % 20;
        int gr = rq * 2 - 1 + r, gc = cc - 1;
        float v = 0.f;
        if (gr >= 0 && gr < 16 && gc >= 0 && gc < 16) {
            const unsigned short* base = out1 + ((size_t)(b * 16 + ic) * 32 + 2 * gr) * 32 + 2 * gc;
            unsigned a01 = *reinterpret_cast<const unsigned*>(base);
            unsigned d01 = *reinterpret_cast<const unsigned*>(base + 32);
            float s0 = sc[ic], s1 = sh[ic];
            v = 0.25f * (fmaxf(fmaf(bf_lo(a01), s0, s1), 0.f) + fmaxf(fmaf(bf_hi(a01), s0, s1), 0.f)
                       + fmaxf(fmaf(bf_lo(d01), s0, s1), 0.f) + fmaxf(fmaf(bf_hi(d01), s0, s1), 0.f));
        }
        smem[ic][r][cc] = v;
    }
    __syncthreads();

    int oc = t & 63, rp = t >> 6;
    float bb = b2[oc];
    float acc[16];
    #pragma unroll
    for (int px = 0; px < 16; px++) acc[px] = bb;

    const float* Wp = W2 + oc;
    float w[9], wn[9];
    #pragma unroll
    for (int k = 0; k < 9; k++) w[k] = Wp[k * 64];
    for (int ic = 0; ic < 16; ic++) {
        if (ic < 15) {
            #pragma unroll
            for (int k = 0; k < 9; k++) wn[k] = Wp[(ic + 1) * 576 + k * 64];
        }
        float rowv[3][18];
        #pragma unroll
        for (int dy = 0; dy < 3; dy++) {
            const float* rb = &smem[ic][rp + dy][0];
            float4 a = *reinterpret_cast<const float4*>(rb);
            float4 bq = *reinterpret_cast<const float4*>(rb + 4);
            float4 cq = *reinterpret_cast<const float4*>(rb + 8);
            float4 dq = *reinterpret_cast<const float4*>(rb + 12);
            float2 e2 = *reinterpret_cast<const float2*>(rb + 16);
            rowv[dy][0]=a.x;   rowv[dy][1]=a.y;   rowv[dy][2]=a.z;   rowv[dy][3]=a.w;
            rowv[dy][4]=bq.x;  rowv[dy][5]=bq.y;  rowv[dy][6]=bq.z;  rowv[dy][7]=bq.w;
            rowv[dy][8]=cq.x;  rowv[dy][9]=cq.y;  rowv[dy][10]=cq.z; rowv[dy][11]=cq.w;
            rowv[dy][12]=dq.x; rowv[dy][13]=dq.y; rowv[dy][14]=dq.z; rowv[dy][15]=dq.w;
            rowv[dy][16]=e2.x; rowv[dy][17]=e2.y;
        }
        #pragma unroll
        for (int dy = 0; dy < 3; dy++)
            #pragma unroll
            for (int px = 0; px < 16; px++) {
                float a = acc[px];
                a = fmaf(w[dy*3+0], rowv[dy][px],   a);
                a = fmaf(w[dy*3+1], rowv[dy][px+1], a);
                a = fmaf(w[dy*3+2], rowv[dy][px+2], a);
                acc[px] = a;
            }
        if (ic < 15) {
            #pragma unroll
            for (int k = 0; k < 9; k++) w[k] = wn[k];
        }
    }
    int row = rq * 2 + rp;
    unsigned short* outb = out2 + ((size_t)b * 64 + oc) * 256 + row * 16;
    uint4 p0, p1;
    p0.x = (unsigned)f2bf(acc[0])  | ((unsigned)f2bf(acc[1])  << 16);
    p0.y = (unsigned)f2bf(acc[2])  | ((unsigned)f2bf(acc[3])  << 16);
    p0.z = (unsigned)f2bf(acc[4])  | ((unsigned)f2bf(acc[5])  << 16);
    p0.w = (unsigned)f2bf(acc[6])  | ((unsigned)f2bf(acc[7])  << 16);
    p1.x = (unsigned)f2bf(acc[8])  | ((unsigned)f2bf(acc[9])  << 16);
    p1.y = (unsigned)f2bf(acc[10]) | ((unsigned)f2bf(acc[11]) << 16);
    p1.z = (unsigned)f2bf(acc[12]) | ((unsigned)f2bf(acc[13]) << 16);
    p1.w = (unsigned)f2bf(acc[14]) | ((unsigned)f2bf(acc[15]) << 16);
    *reinterpret_cast<uint4*>(outb)     = p0;
    *reinterpret_cast<uint4*>(outb + 8) = p1;
    float sv = 0.f, qv = 0.f;
    #pragma unroll
    for (int px = 0; px < 16; px++) { sv += acc[px]; qv += acc[px] * acc[px]; }
    int g = oc >> 4;
    atomicAdd(&rs[g], sv); atomicAdd(&rs[4 + g], qv);
    __syncthreads();
    if (t < 8) atomicAdd(&stats[8 + t], rs[t]);
}

// ---------------- conv3 (+fused bn2/relu/pool): 64->128 ch; grid 1024 x 128thr ----
__global__ __launch_bounds__(128) void conv3_kernel(const unsigned short* __restrict__ out2,
                                                    const float* __restrict__ W3,
                                                    const float* __restrict__ b3,
                                                    const float* __restrict__ bn2g,
                                                    const float* __restrict__ bn2b,
                                                    unsigned short* __restrict__ out3,
                                                    float* __restrict__ stats)
{
    __shared__ float smem[64][4][12];
    __shared__ float rs[8];
    __shared__ float sc[64], sh[64];
    int b = blockIdx.x >> 2, rh = blockIdx.x & 3;
    int t = threadIdx.x;
    if (t < 8) rs[t] = 0.f;
    if (t < 64) {
        const float invN = 1.0f / 1048576.0f;
        float var = 0.f;
        #pragma unroll
        for (int g = 0; g < 4; g++) {
            float S = stats[8 + g], Q = stats[12 + g];
            var += Q - S * S * invN;
        }
        var *= invN;
        float inv = 1.0f / sqrtf(var + 1e-5f);
        float scale = bn2g[t & 15] * inv;
        sc[t] = scale;
        sh[t] = bn2b[t] - stats[8 + (t >> 4)] * invN * scale;
    }
    __syncthreads();
    for (int i = t; i < 3072; i += 128) {
        int ic = i / 48, rem = i % 48, r = rem / 12, cc = rem % 12;
        int gr = rh * 2 - 1 + r, gc = cc - 1;
        float v = 0.f;
        if (gr >= 0 && gr < 8 && gc >= 0 && gc < 8) {
            const unsigned short* base = out2 + ((size_t)(b * 64 + ic) * 16 + 2 * gr) * 16 + 2 * gc;
            unsigned a01 = *reinterpret_cast<const unsigned*>(base);
            unsigned d01 = *reinterpret_cast<const unsigned*>(base + 16);
            float s0 = sc[ic], s1 = sh[ic];
            v = 0.25f * (fmaxf(fmaf(bf_lo(a01), s0, s1), 0.f) + fmaxf(fmaf(bf_hi(a01), s0, s1), 0.f)
                       + fmaxf(fmaf(bf_lo(d01), s0, s1), 0.f) + fmaxf(fmaf(bf_hi(d01), s0, s1), 0.f));
        }
        smem[ic][r][cc] = v;
    }
    __syncthreads();

    int oc = t;   // 128 threads = 128 oc
    float bb = b3[oc];
    float acc[16];
    #pragma unroll
    for (int px = 0; px < 16; px++) acc[px] = bb;

    const float* Wp = W3 + oc;
    float w[9], wn[9];
    #pragma unroll
    for (int k = 0; k < 9; k++) w[k] = Wp[k * 128];
    for (int ic = 0; ic < 64; ic++) {
        if (ic < 63) {
            #pragma unroll
            for (int k = 0; k < 9; k++) wn[k] = Wp[(ic + 1) * 1152 + k * 128];
        }
        float rowv[4][12];
        #pragma unroll
        for (int r = 0; r < 4; r++) {
            const float* rb = &smem[ic][r][0];
            float4 a = *reinterpret_cast<const float4*>(rb);
            float4 bq = *reinterpret_cast<const float4*>(rb + 4);
            float4 cq = *reinterpret_cast<const float4*>(rb + 8);
            rowv[r][0]=a.x;  rowv[r][1]=a.y;  rowv[r][2]=a.z;  rowv[r][3]=a.w;
            rowv[r][4]=bq.x; rowv[r][5]=bq.y; rowv[r][6]=bq.z; rowv[r][7]=bq.w;
            rowv[r][8]=cq.x; rowv[r][9]=cq.y; rowv[r][10]=cq.z; rowv[r][11]=cq.w;
        }
        #pragma unroll
        for (int orow = 0; orow < 2; orow++)
            #pragma unroll
            for (int dy = 0; dy < 3; dy++)
                #pragma unroll
                for (int px = 0; px < 8; px++) {
                    float a = acc[orow * 8 + px];
                    a = fmaf(w[dy*3+0], rowv[orow + dy][px],   a);
                    a = fmaf(w[dy*3+1], rowv[orow + dy][px+1], a);
                    a = fmaf(w[dy*3+2], rowv[orow + dy][px+2], a);
                    acc[orow * 8 + px] = a;
                }
        if (ic < 63) {
            #pragma unroll
            for (int k = 0; k < 9; k++) w[k] = wn[k];
        }
    }
    unsigned short* outb = out3 + ((size_t)b * 128 + oc) * 64 + rh * 16;
    uint4 p0, p1;
    p0.x = (unsigned)f2bf(acc[0])  | ((unsigned)f2bf(acc[1])  << 16);
    p0.y = (unsigned)f2bf(acc[2])  | ((unsigned)f2bf(acc[3])  << 16);
    p0.z = (unsigned)f2bf(acc[4])  | ((unsigned)f2bf(acc[5])  << 16);
    p0.w = (unsigned)f2bf(acc[6])  | ((unsigned)f2bf(acc[7])  << 16);
    p1.x = (unsigned)f2bf(acc[8])  | ((unsigned)f2bf(acc[9])  << 16);
    p1.y = (unsigned)f2bf(acc[10]) | ((unsigned)f2bf(acc[11]) << 16);
    p1.z = (unsigned)f2bf(acc[12]) | ((unsigned)f2bf(acc[13]) << 16);
    p1.w = (unsigned)f2bf(acc[14]) | ((unsigned)f2bf(acc[15]) << 16);
    *reinterpret_cast<uint4*>(outb)     = p0;
    *reinterpret_cast<uint4*>(outb + 8) = p1;
    float sv = 0.f, qv = 0.f;
    #pragma unroll
    for (int px = 0; px < 16; px++) { sv += acc[px]; qv += acc[px] * acc[px]; }
    int g = oc >> 5;
    atomicAdd(&rs[g], sv); atomicAdd(&rs[4 + g], qv);
    __syncthreads();
    if (t < 8) atomicAdd(&stats[16 + t], rs[t]);
}

// ---------------- fc (+fused bn3/relu/pool staging): [256,2048]@[2048,16]+b ----
__global__ __launch_bounds__(256) void fc_kernel(const unsigned short* __restrict__ out3,
                                                 const float* __restrict__ WFC,
                                                 const float* __restrict__ fcb,
                                                 const float* __restrict__ bn3g,
                                                 const float* __restrict__ bn3b,
                                                 const float* __restrict__ stats,
                                                 float* __restrict__ out)
{
    __shared__ float p3s[2048];
    __shared__ float sc[128], sh[128];
    __shared__ float red[256];
    int b = blockIdx.x, t = threadIdx.x;
    if (t < 128) {
        const float invN = 1.0f / 524288.0f;
        float var = 0.f;
        #pragma unroll
        for (int g = 0; g < 4; g++) {
            float S = stats[16 + g], Q = stats[20 + g];
            var += Q - S * S * invN;
        }
        var *= invN;
        float inv = 1.0f / sqrtf(var + 1e-5f);
        float scale = bn3g[t & 31] * inv;
        sc[t] = scale;
        sh[t] = bn3b[t] - stats[16 + (t >> 5)] * invN * scale;
    }
    __syncthreads();
    for (int i = t; i < 2048; i += 256) {
        int c = i >> 4, rem = i & 15, pr = rem >> 2, pc = rem & 3;
        const unsigned short* base = out3 + ((size_t)(b * 128 + c) * 8 + 2 * pr) * 8 + 2 * pc;
        unsigned a01 = *reinterpret_cast<const unsigned*>(base);
        unsigned d01 = *reinterpret_cast<const unsigned*>(base + 8);
        float s0 = sc[c], s1 = sh[c];
        p3s[i] = 0.25f * (fmaxf(fmaf(bf_lo(a01), s0, s1), 0.f) + fmaxf(fmaf(bf_hi(a01), s0, s1), 0.f)
                        + fmaxf(fmaf(bf_lo(d01), s0, s1), 0.f) + fmaxf(fmaf(bf_hi(d01), s0, s1), 0.f));
    }
    __syncthreads();
    int col = t & 15, fr = t >> 4;
    float s = 0.f;
    for (int i = 0; i < 128; i++) {
        int f = i * 16 + fr;
        s = fmaf(p3s[f], WFC[f * 16 + col], s);
    }
    red[t] = s;
    __syncthreads();
    for (int st = 128; st >= 16; st >>= 1) {
        if (t < st) red[t] += red[t + st];
        __syncthreads();
    }
    if (t < 16) out[b * 16 + t] = red[t] + fcb[t];
}

// ---------------- launch ----------------
extern "C" void kernel_launch(void* const* d_in, const int* in_sizes, int n_in,
                              void* d_out, int out_size, void* d_ws, size_t ws_size,
                              hipStream_t stream)
{
    (void)in_sizes; (void)n_in; (void)out_size; (void)ws_size;
    const float* x     = (const float*)d_in[0];
    const float* w_eca = (const float*)d_in[1];
    const float* l1r = (const float*)d_in[2],  *l1i = (const float*)d_in[3];
    const float* l1j = (const float*)d_in[4],  *l1k = (const float*)d_in[5];
    const float* l1b = (const float*)d_in[6];
    const float* bn1g = (const float*)d_in[7], *bn1b = (const float*)d_in[8];
    const float* l2r = (const float*)d_in[9],  *l2i = (const float*)d_in[10];
    const float* l2j = (const float*)d_in[11], *l2k = (const float*)d_in[12];
    const float* l2b = (const float*)d_in[13];
    const float* bn2g = (const float*)d_in[14], *bn2b = (const float*)d_in[15];
    const float* l3r = (const float*)d_in[16], *l3i = (const float*)d_in[17];
    const float* l3j = (const float*)d_in[18], *l3k = (const float*)d_in[19];
    const float* l3b = (const float*)d_in[20];
    const float* bn3g = (const float*)d_in[21], *bn3b = (const float*)d_in[22];
    const float* fcr = (const float*)d_in[23], *fci = (const float*)d_in[24];
    const float* fcj = (const float*)d_in[25], *fck = (const float*)d_in[26];
    const float* fcb = (const float*)d_in[27];

    float* ws   = (float*)d_ws;
    float* outp = (float*)d_out;
    unsigned short* o1 = (unsigned short*)(ws + WS_OUT1);
    unsigned short* o2 = (unsigned short*)(ws + WS_OUT2);
    unsigned short* o3 = (unsigned short*)(ws + WS_OUT3);

    prepmean_kernel<<<1024, 256, 0, stream>>>(x, ws + WS_POOL,
        l1r, l1i, l1j, l1k, l2r, l2i, l2j, l2k, l3r, l3i, l3j, l3k,
        fcr, fci, fcj, fck, ws);
    conv1_kernel<<<2048, 256, 0, stream>>>(x, ws + WS_POOL, w_eca, ws + WS_W1,
                                           l1b, o1, ws + WS_STATS);
    conv2_kernel<<<2048, 128, 0, stream>>>(o1, ws + WS_W2, l2b, bn1g, bn1b,
                                           o2, ws + WS_STATS);
    conv3_kernel<<<1024, 128, 0, stream>>>(o2, ws + WS_W3, l3b, bn2g, bn2b,
                                           o3, ws + WS_STATS);
    fc_kernel<<<256, 256, 0, stream>>>(o3, ws + WS_WFC, fcb, bn3g, bn3b,
                                       ws + WS_STATS, outp);
}

// Round 12
// 181.317 us; speedup vs baseline: 1.0769x; 1.0769x over previous
//
#include <hip/hip_runtime.h>
#include <math.h>

// ---------------- workspace layout (float offsets) ----------------
#define WS_STATS 0         // 24 floats: [layer][S_r..S_k, Q_r..Q_k]
#define WS_W1    32        // 16*4*9   = 576      layout [s(4)][k(9)][oc(16)]
#define WS_W2    640       // 64*16*9  = 9216     layout [ic(16)][k(9)][oc(64)]
#define WS_W3    9856      // 128*64*9 = 73728    layout [ic(64)][k(9)][oc(128)]
#define WS_WFC   83584     // 2048*16  = 32768    layout [row(2048)][col(16)]
#define WS_POOL  116352    // 256*200  = 51200
#define WS_OUT1  167552    // 256*16*32*32 = 4194304
#define WS_OUT2  4361856   // 256*64*16*16 = 4194304
#define WS_OUT3  8556160   // 256*128*8*8  = 2097152

// Hamilton block table: T[a][b] -> (component, sign)
__device__ const int   d_TC[4][4] = {{0,1,2,3},{1,0,3,2},{2,3,0,1},{3,2,1,0}};
__device__ const float d_TS[4][4] = {{1.f,-1.f,-1.f,-1.f},{1.f,1.f,-1.f,1.f},
                                     {1.f,1.f,1.f,-1.f},{1.f,-1.f,1.f,1.f}};

// ---------------- persistent prep+mean: grid 1024, 50 channels/block ----------------
__global__ __launch_bounds__(256) void prepmean_kernel(
    const float* __restrict__ x, float* __restrict__ pooled,
    const float* l1r, const float* l1i, const float* l1j, const float* l1k,
    const float* l2r, const float* l2i, const float* l2j, const float* l2k,
    const float* l3r, const float* l3i, const float* l3j, const float* l3k,
    const float* fcr, const float* fci, const float* fcj, const float* fck,
    float* ws)
{
    const int blk = blockIdx.x, t = threadIdx.x;
    const int lane = t & 63, wv = t >> 6;
    int tid = blk * 256 + t;
    const int nthr = 1024 * 256;
    if (tid < 24) ws[WS_STATS + tid] = 0.f;

    { // W1: [s(4)][k(9)][oc(16)]
        const float* cp[4] = {l1r, l1i, l1j, l1k};
        for (int e = tid; e < 576; e += nthr) {
            int s = e / 144, rem = e % 144, k = rem / 16, oc = rem % 16;
            int p = oc >> 2, o = oc & 3;
            ws[WS_W1 + e] = d_TS[p][s] * cp[d_TC[p][s]][o * 9 + k];
        }
    }
    { // W2: [ic(16)][k(9)][oc(64)]
        const float* cp[4] = {l2r, l2i, l2j, l2k};
        for (int e = tid; e < 9216; e += nthr) {
            int oc = e & 63, k = (e >> 6) % 9, ic = e / 576;
            int p = oc >> 4, o = oc & 15, s = ic >> 2, ii = ic & 3;
            ws[WS_W2 + e] = d_TS[p][s] * cp[d_TC[p][s]][(o * 4 + ii) * 9 + k];
        }
    }
    { // W3: [ic(64)][k(9)][oc(128)]
        const float* cp[4] = {l3r, l3i, l3j, l3k};
        for (int e = tid; e < 73728; e += nthr) {
            int oc = e & 127, k = (e >> 7) % 9, ic = e / 1152;
            int p = oc >> 5, o = oc & 31, s = ic >> 4, ii = ic & 15;
            ws[WS_W3 + e] = d_TS[p][s] * cp[d_TC[p][s]][(o * 16 + ii) * 9 + k];
        }
    }
    { // WFC: 2048 x 16
        const float* cp[4] = {fcr, fci, fcj, fck};
        for (int e = tid; e < 32768; e += nthr) {
            int R = e >> 4, C = e & 15;
            int p = R >> 9, rr = R & 511, q = C >> 2, cc = C & 3;
            ws[WS_WFC + e] = d_TS[q][p] * cp[d_TC[q][p]][rr * 4 + cc];
        }
    }
    // channel means: 50 channels per block, one channel per wave-iteration
    int base = blk * 50;
    for (int i = wv; i < 50; i += 4) {
        const float4* src = reinterpret_cast<const float4*>(x + (size_t)(base + i) * 1024);
        float s = 0.f;
        #pragma unroll
        for (int j = 0; j < 4; j++) {
            float4 v = src[lane + 64 * j];
            s += v.x + v.y + v.z + v.w;
        }
        #pragma unroll
        for (int off = 32; off; off >>= 1) s += __shfl_xor(s, off, 64);
        if (lane == 0) pooled[base + i] = s * (1.0f / 1024.0f);
    }
}

// ---------------- conv1 (+in-block top-3): 4->16 ch, 32x32; grid 2048 ----
__global__ __launch_bounds__(256) void conv1_kernel(const float* __restrict__ x,
                                                    const float* __restrict__ pooled,
                                                    const float* __restrict__ w_eca,
                                                    const float* __restrict__ W1,
                                                    const float* __restrict__ b1,
                                                    float* __restrict__ out1,
                                                    float* __restrict__ stats)
{
    __shared__ float smem[3][6][36];
    __shared__ float rs[8];
    __shared__ int idx_s[3];
    int b = blockIdx.x >> 3, rg = blockIdx.x & 7;
    int t = threadIdx.x;
    if (t < 8) rs[t] = 0.f;
    if (t < 64) {
        float w = w_eca[0];
        float v[4]; int c[4];
        #pragma unroll
        for (int i = 0; i < 4; i++) {
            int ch = t + 64 * i;
            c[i] = ch;
            v[i] = (ch < 200) ? w * pooled[b * 200 + ch] : -INFINITY;
        }
        for (int k = 0; k < 3; k++) {
            float bv = -INFINITY; int bi = 0x3fffffff;
            #pragma unroll
            for (int i = 0; i < 4; i++)
                if (v[i] > bv || (v[i] == bv && c[i] < bi)) { bv = v[i]; bi = c[i]; }
            for (int off = 32; off; off >>= 1) {
                float ov = __shfl_xor(bv, off, 64);
                int   oi = __shfl_xor(bi, off, 64);
                if (ov > bv || (ov == bv && oi < bi)) { bv = ov; bi = oi; }
            }
            if (t == 0) idx_s[k] = bi;
            #pragma unroll
            for (int i = 0; i < 4; i++) if (c[i] == bi) v[i] = -INFINITY;
        }
    }
    __syncthreads();
    for (int i = t; i < 648; i += 256) {
        int s = i / 216, rem = i % 216, r = rem / 36, cc = rem % 36;
        int gr = rg * 4 - 1 + r, gc = cc - 1;
        float v = 0.f;
        if (gr >= 0 && gr < 32 && gc >= 0 && gc < 32)
            v = x[((size_t)b * 200 + idx_s[s]) * 1024 + gr * 32 + gc];
        smem[s][r][cc] = v;
    }
    __syncthreads();

    int oc = t & 15, rp = (t >> 4) & 3, ch = t >> 6;
    float bb = b1[oc];
    float acc[8];
    #pragma unroll
    for (int px = 0; px < 8; px++) acc[px] = bb;

    #pragma unroll
    for (int s = 0; s < 3; s++) {
        float w[9];
        #pragma unroll
        for (int k = 0; k < 9; k++) w[k] = W1[((s + 1) * 9 + k) * 16 + oc];
        float rowv[3][12];
        #pragma unroll
        for (int dy = 0; dy < 3; dy++) {
            const float* rb = &smem[s][rp + dy][ch * 8];
            float4 a = *reinterpret_cast<const float4*>(rb);
            float4 bq = *reinterpret_cast<const float4*>(rb + 4);
            float4 cq = *reinterpret_cast<const float4*>(rb + 8);
            rowv[dy][0]=a.x;  rowv[dy][1]=a.y;  rowv[dy][2]=a.z;  rowv[dy][3]=a.w;
            rowv[dy][4]=bq.x; rowv[dy][5]=bq.y; rowv[dy][6]=bq.z; rowv[dy][7]=bq.w;
            rowv[dy][8]=cq.x; rowv[dy][9]=cq.y; rowv[dy][10]=cq.z; rowv[dy][11]=cq.w;
        }
        #pragma unroll
        for (int dy = 0; dy < 3; dy++)
            #pragma unroll
            for (int px = 0; px < 8; px++) {
                float a = acc[px];
                a = fmaf(w[dy*3+0], rowv[dy][px],   a);
                a = fmaf(w[dy*3+1], rowv[dy][px+1], a);
                a = fmaf(w[dy*3+2], rowv[dy][px+2], a);
                acc[px] = a;
            }
    }
    int row = rg * 4 + rp;
    float* outb = out1 + ((size_t)b * 16 + oc) * 1024 + row * 32 + ch * 8;
    *reinterpret_cast<float4*>(outb)     = make_float4(acc[0], acc[1], acc[2], acc[3]);
    *reinterpret_cast<float4*>(outb + 4) = make_float4(acc[4], acc[5], acc[6], acc[7]);
    float sv = 0.f, qv = 0.f;
    #pragma unroll
    for (int px = 0; px < 8; px++) { sv += acc[px]; qv += acc[px] * acc[px]; }
    int g = oc >> 2;
    atomicAdd(&rs[g], sv); atomicAdd(&rs[4 + g], qv);
    __syncthreads();
    if (t < 8) atomicAdd(&stats[t], rs[t]);
}

// ---------------- conv2 (+fused bn1/relu/pool): 16->64 ch; grid 2048 x 128thr ----
__global__ __launch_bounds__(128) void conv2_kernel(const float* __restrict__ out1,
                                                    const float* __restrict__ W2,
                                                    const float* __restrict__ b2,
                                                    const float* __restrict__ bn1g,
                                                    const float* __restrict__ bn1b,
                                                    float* __restrict__ out2,
                                                    float* __restrict__ stats)
{
    __shared__ float smem[16][4][20];
    __shared__ float rs[8];
    __shared__ float sc[16], sh[16];
    int b = blockIdx.x >> 3, rq = blockIdx.x & 7;
    int t = threadIdx.x;
    if (t < 8) rs[t] = 0.f;
    if (t < 16) {
        const float invN = 1.0f / 1048576.0f;
        float var = 0.f;
        #pragma unroll
        for (int g = 0; g < 4; g++) {
            float S = stats[g], Q = stats[4 + g];
            var += Q - S * S * invN;
        }
        var *= invN;
        float inv = 1.0f / sqrtf(var + 1e-5f);
        float scale = bn1g[t & 3] * inv;
        sc[t] = scale;
        sh[t] = bn1b[t] - stats[t >> 2] * invN * scale;
    }
    __syncthreads();
    for (int i = t; i < 1280; i += 128) {
        int ic = i / 80, rem = i % 80, r = rem / 20, cc = rem % 20;
        int gr = rq * 2 - 1 + r, gc = cc - 1;
        float v = 0.f;
        if (gr >= 0 && gr < 16 && gc >= 0 && gc < 16) {
            const float* base = out1 + ((size_t)(b * 16 + ic) * 32 + 2 * gr) * 32 + 2 * gc;
            float2 a = *reinterpret_cast<const float2*>(base);
            float2 d = *reinterpret_cast<const float2*>(base + 32);
            float s0 = sc[ic], s1 = sh[ic];
            v = 0.25f * (fmaxf(fmaf(a.x, s0, s1), 0.f) + fmaxf(fmaf(a.y, s0, s1), 0.f)
                       + fmaxf(fmaf(d.x, s0, s1), 0.f) + fmaxf(fmaf(d.y, s0, s1), 0.f));
        }
        smem[ic][r][cc] = v;
    }
    __syncthreads();

    int oc = t & 63, rp = t >> 6;
    float bb = b2[oc];
    float acc[16];
    #pragma unroll
    for (int px = 0; px < 16; px++) acc[px] = bb;

    const float* Wp = W2 + oc;
    float w[9], wn[9];
    #pragma unroll
    for (int k = 0; k < 9; k++) w[k] = Wp[k * 64];
    for (int ic = 0; ic < 16; ic++) {
        if (ic < 15) {
            #pragma unroll
            for (int k = 0; k < 9; k++) wn[k] = Wp[(ic + 1) * 576 + k * 64];
        }
        float rowv[3][18];
        #pragma unroll
        for (int dy = 0; dy < 3; dy++) {
            const float* rb = &smem[ic][rp + dy][0];
            float4 a = *reinterpret_cast<const float4*>(rb);
            float4 bq = *reinterpret_cast<const float4*>(rb + 4);
            float4 cq = *reinterpret_cast<const float4*>(rb + 8);
            float4 dq = *reinterpret_cast<const float4*>(rb + 12);
            float2 e2 = *reinterpret_cast<const float2*>(rb + 16);
            rowv[dy][0]=a.x;   rowv[dy][1]=a.y;   rowv[dy][2]=a.z;   rowv[dy][3]=a.w;
            rowv[dy][4]=bq.x;  rowv[dy][5]=bq.y;  rowv[dy][6]=bq.z;  rowv[dy][7]=bq.w;
            rowv[dy][8]=cq.x;  rowv[dy][9]=cq.y;  rowv[dy][10]=cq.z; rowv[dy][11]=cq.w;
            rowv[dy][12]=dq.x; rowv[dy][13]=dq.y; rowv[dy][14]=dq.z; rowv[dy][15]=dq.w;
            rowv[dy][16]=e2.x; rowv[dy][17]=e2.y;
        }
        #pragma unroll
        for (int dy = 0; dy < 3; dy++)
            #pragma unroll
            for (int px = 0; px < 16; px++) {
                float a = acc[px];
                a = fmaf(w[dy*3+0], rowv[dy][px],   a);
                a = fmaf(w[dy*3+1], rowv[dy][px+1], a);
                a = fmaf(w[dy*3+2], rowv[dy][px+2], a);
                acc[px] = a;
            }
        if (ic < 15) {
            #pragma unroll
            for (int k = 0; k < 9; k++) w[k] = wn[k];
        }
    }
    int row = rq * 2 + rp;
    float* outb = out2 + ((size_t)b * 64 + oc) * 256 + row * 16;
    #pragma unroll
    for (int q4 = 0; q4 < 4; q4++)
        *reinterpret_cast<float4*>(outb + q4 * 4) =
            make_float4(acc[q4*4], acc[q4*4+1], acc[q4*4+2], acc[q4*4+3]);
    float sv = 0.f, qv = 0.f;
    #pragma unroll
    for (int px = 0; px < 16; px++) { sv += acc[px]; qv += acc[px] * acc[px]; }
    int g = oc >> 4;
    atomicAdd(&rs[g], sv); atomicAdd(&rs[4 + g], qv);
    __syncthreads();
    if (t < 8) atomicAdd(&stats[8 + t], rs[t]);
}

// ---------------- conv3 (+fused bn2/relu/pool): 64->128 ch; grid 1024 x 128thr ----
__global__ __launch_bounds__(128) void conv3_kernel(const float* __restrict__ out2,
                                                    const float* __restrict__ W3,
                                                    const float* __restrict__ b3,
                                                    const float* __restrict__ bn2g,
                                                    const float* __restrict__ bn2b,
                                                    float* __restrict__ out3,
                                                    float* __restrict__ stats)
{
    __shared__ float smem[64][4][12];
    __shared__ float rs[8];
    __shared__ float sc[64], sh[64];
    int b = blockIdx.x >> 2, rh = blockIdx.x & 3;
    int t = threadIdx.x;
    if (t < 8) rs[t] = 0.f;
    if (t < 64) {
        const float invN = 1.0f / 1048576.0f;
        float var = 0.f;
        #pragma unroll
        for (int g = 0; g < 4; g++) {
            float S = stats[8 + g], Q = stats[12 + g];
            var += Q - S * S * invN;
        }
        var *= invN;
        float inv = 1.0f / sqrtf(var + 1e-5f);
        float scale = bn2g[t & 15] * inv;
        sc[t] = scale;
        sh[t] = bn2b[t] - stats[8 + (t >> 4)] * invN * scale;
    }
    __syncthreads();
    for (int i = t; i < 3072; i += 128) {
        int ic = i / 48, rem = i % 48, r = rem / 12, cc = rem % 12;
        int gr = rh * 2 - 1 + r, gc = cc - 1;
        float v = 0.f;
        if (gr >= 0 && gr < 8 && gc >= 0 && gc < 8) {
            const float* base = out2 + ((size_t)(b * 64 + ic) * 16 + 2 * gr) * 16 + 2 * gc;
            float2 a = *reinterpret_cast<const float2*>(base);
            float2 d = *reinterpret_cast<const float2*>(base + 16);
            float s0 = sc[ic], s1 = sh[ic];
            v = 0.25f * (fmaxf(fmaf(a.x, s0, s1), 0.f) + fmaxf(fmaf(a.y, s0, s1), 0.f)
                       + fmaxf(fmaf(d.x, s0, s1), 0.f) + fmaxf(fmaf(d.y, s0, s1), 0.f));
        }
        smem[ic][r][cc] = v;
    }
    __syncthreads();

    int oc = t;   // 128 threads = 128 oc
    float bb = b3[oc];
    float acc[16];
    #pragma unroll
    for (int px = 0; px < 16; px++) acc[px] = bb;

    const float* Wp = W3 + oc;
    float w[9], wn[9];
    #pragma unroll
    for (int k = 0; k < 9; k++) w[k] = Wp[k * 128];
    for (int ic = 0; ic < 64; ic++) {
        if (ic < 63) {
            #pragma unroll
            for (int k = 0; k < 9; k++) wn[k] = Wp[(ic + 1) * 1152 + k * 128];
        }
        float rowv[4][12];
        #pragma unroll
        for (int r = 0; r < 4; r++) {
            const float* rb = &smem[ic][r][0];
            float4 a = *reinterpret_cast<const float4*>(rb);
            float4 bq = *reinterpret_cast<const float4*>(rb + 4);
            float4 cq = *reinterpret_cast<const float4*>(rb + 8);
            rowv[r][0]=a.x;  rowv[r][1]=a.y;  rowv[r][2]=a.z;  rowv[r][3]=a.w;
            rowv[r][4]=bq.x; rowv[r][5]=bq.y; rowv[r][6]=bq.z; rowv[r][7]=bq.w;
            rowv[r][8]=cq.x; rowv[r][9]=cq.y; rowv[r][10]=cq.z; rowv[r][11]=cq.w;
        }
        #pragma unroll
        for (int orow = 0; orow < 2; orow++)
            #pragma unroll
            for (int dy = 0; dy < 3; dy++)
                #pragma unroll
                for (int px = 0; px < 8; px++) {
                    float a = acc[orow * 8 + px];
                    a = fmaf(w[dy*3+0], rowv[orow + dy][px],   a);
                    a = fmaf(w[dy*3+1], rowv[orow + dy][px+1], a);
                    a = fmaf(w[dy*3+2], rowv[orow + dy][px+2], a);
                    acc[orow * 8 + px] = a;
                }
        if (ic < 63) {
            #pragma unroll
            for (int k = 0; k < 9; k++) w[k] = wn[k];
        }
    }
    float* outb = out3 + ((size_t)b * 128 + oc) * 64 + rh * 16;
    #pragma unroll
    for (int q4 = 0; q4 < 4; q4++)
        *reinterpret_cast<float4*>(outb + q4 * 4) =
            make_float4(acc[q4*4], acc[q4*4+1], acc[q4*4+2], acc[q4*4+3]);
    float sv = 0.f, qv = 0.f;
    #pragma unroll
    for (int px = 0; px < 16; px++) { sv += acc[px]; qv += acc[px] * acc[px]; }
    int g = oc >> 5;
    atomicAdd(&rs[g], sv); atomicAdd(&rs[4 + g], qv);
    __syncthreads();
    if (t < 8) atomicAdd(&stats[16 + t], rs[t]);
}

// ---------------- fc (+fused bn3/relu/pool staging): [256,2048]@[2048,16]+b ----
__global__ __launch_bounds__(256) void fc_kernel(const float* __restrict__ out3,
                                                 const float* __restrict__ WFC,
                                                 const float* __restrict__ fcb,
                                                 const float* __restrict__ bn3g,
                                                 const float* __restrict__ bn3b,
                                                 const float* __restrict__ stats,
                                                 float* __restrict__ out)
{
    __shared__ float p3s[2048];
    __shared__ float sc[128], sh[128];
    __shared__ float red[256];
    int b = blockIdx.x, t = threadIdx.x;
    if (t < 128) {
        const float invN = 1.0f / 524288.0f;
        float var = 0.f;
        #pragma unroll
        for (int g = 0; g < 4; g++) {
            float S = stats[16 + g], Q = stats[20 + g];
            var += Q - S * S * invN;
        }
        var *= invN;
        float inv = 1.0f / sqrtf(var + 1e-5f);
        float scale = bn3g[t & 31] * inv;
        sc[t] = scale;
        sh[t] = bn3b[t] - stats[16 + (t >> 5)] * invN * scale;
    }
    __syncthreads();
    for (int i = t; i < 2048; i += 256) {
        int c = i >> 4, rem = i & 15, pr = rem >> 2, pc = rem & 3;
        const float* base = out3 + ((size_t)(b * 128 + c) * 8 + 2 * pr) * 8 + 2 * pc;
        float2 a = *reinterpret_cast<const float2*>(base);
        float2 d = *reinterpret_cast<const float2*>(base + 8);
        float s0 = sc[c], s1 = sh[c];
        p3s[i] = 0.25f * (fmaxf(fmaf(a.x, s0, s1), 0.f) + fmaxf(fmaf(a.y, s0, s1), 0.f)
                        + fmaxf(fmaf(d.x, s0, s1), 0.f) + fmaxf(fmaf(d.y, s0, s1), 0.f));
    }
    __syncthreads();
    int col = t & 15, fr = t >> 4;
    float s = 0.f;
    for (int i = 0; i < 128; i++) {
        int f = i * 16 + fr;
        s = fmaf(p3s[f], WFC[f * 16 + col], s);
    }
    red[t] = s;
    __syncthreads();
    for (int st = 128; st >= 16; st >>= 1) {
        if (t < st) red[t] += red[t + st];
        __syncthreads();
    }
    if (t < 16) out[b * 16 + t] = red[t] + fcb[t];
}

// ---------------- launch ----------------
extern "C" void kernel_launch(void* const* d_in, const int* in_sizes, int n_in,
                              void* d_out, int out_size, void* d_ws, size_t ws_size,
                              hipStream_t stream)
{
    (void)in_sizes; (void)n_in; (void)out_size; (void)ws_size;
    const float* x     = (const float*)d_in[0];
    const float* w_eca = (const float*)d_in[1];
    const float* l1r = (const float*)d_in[2],  *l1i = (const float*)d_in[3];
    const float* l1j = (const float*)d_in[4],  *l1k = (const float*)d_in[5];
    const float* l1b = (const float*)d_in[6];
    const float* bn1g = (const float*)d_in[7], *bn1b = (const float*)d_in[8];
    const float* l2r = (const float*)d_in[9],  *l2i = (const float*)d_in[10];
    const float* l2j = (const float*)d_in[11], *l2k = (const float*)d_in[12];
    const float* l2b = (const float*)d_in[13];
    const float* bn2g = (const float*)d_in[14], *bn2b = (const float*)d_in[15];
    const float* l3r = (const float*)d_in[16], *l3i = (const float*)d_in[17];
    const float* l3j = (const float*)d_in[18], *l3k = (const float*)d_in[19];
    const float* l3b = (const float*)d_in[20];
    const float* bn3g = (const float*)d_in[21], *bn3b = (const float*)d_in[22];
    const float* fcr = (const float*)d_in[23], *fci = (const float*)d_in[24];
    const float* fcj = (const float*)d_in[25], *fck = (const float*)d_in[26];
    const float* fcb = (const float*)d_in[27];

    float* ws   = (float*)d_ws;
    float* outp = (float*)d_out;

    prepmean_kernel<<<1024, 256, 0, stream>>>(x, ws + WS_POOL,
        l1r, l1i, l1j, l1k, l2r, l2i, l2j, l2k, l3r, l3i, l3j, l3k,
        fcr, fci, fcj, fck, ws);
    conv1_kernel<<<2048, 256, 0, stream>>>(x, ws + WS_POOL, w_eca, ws + WS_W1,
                                           l1b, ws + WS_OUT1, ws + WS_STATS);
    conv2_kernel<<<2048, 128, 0, stream>>>(ws + WS_OUT1, ws + WS_W2, l2b, bn1g, bn1b,
                                           ws + WS_OUT2, ws + WS_STATS);
    conv3_kernel<<<1024, 128, 0, stream>>>(ws + WS_OUT2, ws + WS_W3, l3b, bn2g, bn2b,
                                           ws + WS_OUT3, ws + WS_STATS);
    fc_kernel<<<256, 256, 0, stream>>>(ws + WS_OUT3, ws + WS_WFC, fcb, bn3g, bn3b,
                                       ws + WS_STATS, outp);
}